// Round 1
// baseline (78.477 us; speedup 1.0000x reference)
//
#include <hip/hip_runtime.h>
#include <hip/hip_bf16.h>

typedef __attribute__((ext_vector_type(8))) short s16x8;
typedef __attribute__((ext_vector_type(4))) float f32x4;

#define NEGC 1000000000000.0f

constexpr int B_ = 8, S_ = 512, H_ = 768;
constexpr int ENT = 12, ARG = 16;
constexpr int NC = 320;              // 128 + 24 + 128 + 32 = 312, padded to 320
constexpr int ROWS = B_ * S_;        // 4096
constexpr size_t OUT_ENT = (size_t)B_ * ENT * S_ * S_;  // 25,165,824

static __device__ __forceinline__ unsigned short f2bf(float x) {
  return __builtin_bit_cast(unsigned short, __float2bfloat16(x));
}

// ---------------------------------------------------------------------------
// Kernel 1: convert X to bf16; build transposed concat weight Wt[320][768] bf16
// and concat bias bcat[320] fp32.
// ---------------------------------------------------------------------------
__global__ __launch_bounds__(256) void k_prep(
    const float* __restrict__ X,
    const float* __restrict__ W1, const float* __restrict__ b1,
    const float* __restrict__ W2, const float* __restrict__ b2,
    const float* __restrict__ Wa1, const float* __restrict__ ba1,
    const float* __restrict__ Wa2, const float* __restrict__ ba2,
    __hip_bfloat16* __restrict__ Xb,
    __hip_bfloat16* __restrict__ Wt,
    float* __restrict__ bcat) {
  int idx = blockIdx.x * 256 + threadIdx.x;
  const int nx = ROWS * H_ / 4;  // 786432 float4 tasks
  if (idx < nx) {
    float4 v = reinterpret_cast<const float4*>(X)[idx];
    ushort4 o;
    o.x = f2bf(v.x); o.y = f2bf(v.y); o.z = f2bf(v.z); o.w = f2bf(v.w);
    reinterpret_cast<ushort4*>(Xb)[idx] = o;
    return;
  }
  idx -= nx;
  if (idx < NC * H_) {
    int n = idx / H_;
    int k = idx - n * H_;
    float v = 0.0f;
    if (n < 128)      v = W1[k * 128 + n];
    else if (n < 152) v = W2[k * 24 + (n - 128)];
    else if (n < 280) v = Wa1[k * 128 + (n - 152)];
    else if (n < 312) v = Wa2[k * 32 + (n - 280)];
    reinterpret_cast<unsigned short*>(Wt)[(size_t)n * H_ + k] = f2bf(v);
    return;
  }
  idx -= NC * H_;
  if (idx < NC) {
    int n = idx;
    float v = 0.0f;
    if (n < 128)      v = b1[n];
    else if (n < 152) v = b2[n - 128];
    else if (n < 280) v = ba1[n - 152];
    else if (n < 312) v = ba2[n - 280];
    bcat[n] = v;
  }
}

// ---------------------------------------------------------------------------
// Kernel 2: P[4096][320] = X[4096][768] @ Wcat[768][320] + bcat  (bf16 MFMA)
// Direct-from-global fragments: A = X row-major, B = Wt (N-major, i.e. W^T).
// Block = 4 waves, 64x64 tile; wave = 32x32 (2x2 fragments of 16x16x32).
// ---------------------------------------------------------------------------
__global__ __launch_bounds__(256) void k_gemm(
    const __hip_bfloat16* __restrict__ Xb,
    const __hip_bfloat16* __restrict__ Wt,
    const float* __restrict__ bcat,
    float* __restrict__ P) {
  const int lane = threadIdx.x & 63;
  const int wid  = threadIdx.x >> 6;
  const int row0 = blockIdx.y * 64 + (wid >> 1) * 32;
  const int col0 = blockIdx.x * 64 + (wid & 1) * 32;
  const int rl   = lane & 15;
  const int kseg = (lane >> 4) * 8;
  const short* Xs = reinterpret_cast<const short*>(Xb);
  const short* Ws = reinterpret_cast<const short*>(Wt);
  f32x4 acc[2][2] = {};
#pragma unroll 4
  for (int kk = 0; kk < H_; kk += 32) {
    s16x8 a[2], bb[2];
#pragma unroll
    for (int i = 0; i < 2; ++i) {
      a[i]  = *reinterpret_cast<const s16x8*>(Xs + (size_t)(row0 + i * 16 + rl) * H_ + kk + kseg);
      bb[i] = *reinterpret_cast<const s16x8*>(Ws + (size_t)(col0 + i * 16 + rl) * H_ + kk + kseg);
    }
#pragma unroll
    for (int i = 0; i < 2; ++i)
#pragma unroll
      for (int j = 0; j < 2; ++j)
        acc[i][j] = __builtin_amdgcn_mfma_f32_16x16x32_bf16(a[i], bb[j], acc[i][j], 0, 0, 0);
  }
#pragma unroll
  for (int i = 0; i < 2; ++i)
#pragma unroll
    for (int j = 0; j < 2; ++j) {
      int col = col0 + j * 16 + rl;
      float bv = bcat[col];
#pragma unroll
      for (int q = 0; q < 4; ++q) {
        int row = row0 + i * 16 + (lane >> 4) * 4 + q;
        P[(size_t)row * NC + col] = acc[i][j][q] + bv;
      }
    }
}

// ---------------------------------------------------------------------------
// Kernel 3: de-interleave P into roped q/k (bf16, for MFMA) and biases (fp32).
// One 64-lane group per row: lanes 0..31 = ent rope pair p, 32..63 = arg pair.
// ---------------------------------------------------------------------------
__global__ __launch_bounds__(256) void k_rope(
    const float* __restrict__ P,
    __hip_bfloat16* __restrict__ qwe, __hip_bfloat16* __restrict__ kwe,
    __hip_bfloat16* __restrict__ qwa, __hip_bfloat16* __restrict__ kwa,
    float* __restrict__ kbe, float* __restrict__ qbe,
    float* __restrict__ kba, float* __restrict__ qba) {
  int gt = blockIdx.x * 256 + threadIdx.x;
  int row = gt >> 6;
  int lane = gt & 63;
  if (row >= ROWS) return;
  int b = row >> 9, m = row & 511;
  const float* Pr = P + (size_t)row * NC;
  {
    int p = lane & 31;
    int grp = lane >> 5;  // 0 = ent, 1 = arg
    const float* src = Pr + (grp ? 152 : 0) + 4 * p;
    float4 o = *reinterpret_cast<const float4*>(src);
    // inv = 10000^(-p/32) = 2^(-p*log2(10000)/32)
    float inv = exp2f(-(float)p * 0.4152410118609203f);
    float ang = (float)m * inv;
    float s, c;
    sincosf(ang, &s, &c);
    float q0 = o.x, k0 = o.y, q1 = o.z, k1 = o.w;
    __hip_bfloat16* qd = (grp ? qwa : qwe) + (size_t)row * 64 + 2 * p;
    __hip_bfloat16* kd = (grp ? kwa : kwe) + (size_t)row * 64 + 2 * p;
    qd[0] = __float2bfloat16(q0 * c - q1 * s);
    qd[1] = __float2bfloat16(q1 * c + q0 * s);
    kd[0] = __float2bfloat16(k0 * c - k1 * s);
    kd[1] = __float2bfloat16(k1 * c + k0 * s);
  }
  if (lane < 24) {  // ent bias: cols 128..151, even->kb, odd->qb
    float v = Pr[128 + lane] * 0.5f;
    int t = lane >> 1;
    float* dst = (lane & 1) ? qbe : kbe;
    dst[((size_t)b * ENT + t) * S_ + m] = v;
  }
  if (lane < 32) {  // arg bias: cols 280..311
    float v = Pr[280 + lane] * 0.5f;
    int t = lane >> 1;
    float* dst = (lane & 1) ? qba : kba;
    dst[((size_t)b * ARG + t) * S_ + m] = v;
  }
}

// ---------------------------------------------------------------------------
// Kernel 4: the big broadcast-write. Block = (n-tile 64, m-tile 64, b).
// 4 waves; wave w owns rows m0+16w..+15 x all 64 cols.
// qk = Q K^T / 8 via 8 MFMAs straight from global (q/k arrays are L2-resident),
// then stream 12+16 head planes with bias/mask/tril applied.
// ---------------------------------------------------------------------------
__global__ __launch_bounds__(256) void k_bcast(
    const __hip_bfloat16* __restrict__ qwe, const __hip_bfloat16* __restrict__ kwe,
    const __hip_bfloat16* __restrict__ qwa, const __hip_bfloat16* __restrict__ kwa,
    const float* __restrict__ kbe, const float* __restrict__ qbe,
    const float* __restrict__ kba, const float* __restrict__ qba,
    const int* __restrict__ mask,
    float* __restrict__ out) {
  const int lane = threadIdx.x & 63;
  const int w = threadIdx.x >> 6;
  const int b = blockIdx.z;
  const int m0 = blockIdx.y * 64 + w * 16;
  const int n0 = blockIdx.x * 64;
  const int col = lane & 15;
  const int rg = lane >> 4;
  const int kseg = rg * 8;

  float mqv[4], sqv[4];
  int mrow[4];
#pragma unroll
  for (int j = 0; j < 4; ++j) {
    mrow[j] = m0 + rg * 4 + j;
    float mf = (float)mask[b * S_ + mrow[j]];
    mqv[j] = mf; sqv[j] = NEGC * (1.0f - mf);
  }
  float mkv[4], skv[4];
  int ncol[4];
#pragma unroll
  for (int f = 0; f < 4; ++f) {
    ncol[f] = n0 + 16 * f + col;
    float mf = (float)mask[b * S_ + ncol[f]];
    mkv[f] = mf; skv[f] = NEGC * (1.0f - mf);
  }

  // ---------------- ent head group ----------------
  {
    const short* qs = reinterpret_cast<const short*>(qwe);
    const short* ks = reinterpret_cast<const short*>(kwe);
    f32x4 acc[4] = {};
#pragma unroll
    for (int kk = 0; kk < 64; kk += 32) {
      s16x8 a = *reinterpret_cast<const s16x8*>(
          qs + (size_t)(b * S_ + m0 + (lane & 15)) * 64 + kk + kseg);
#pragma unroll
      for (int f = 0; f < 4; ++f) {
        s16x8 bb = *reinterpret_cast<const s16x8*>(
            ks + (size_t)(b * S_ + n0 + 16 * f + (lane & 15)) * 64 + kk + kseg);
        acc[f] = __builtin_amdgcn_mfma_f32_16x16x32_bf16(a, bb, acc[f], 0, 0, 0);
      }
    }
#pragma unroll
    for (int f = 0; f < 4; ++f)
#pragma unroll
      for (int j = 0; j < 4; ++j) acc[f][j] *= 0.125f;

    for (int t = 0; t < ENT; ++t) {
      const float* qbp = qbe + ((size_t)b * ENT + t) * S_;
      const float* kbp = kbe + ((size_t)b * ENT + t) * S_;
      float qv[4];
#pragma unroll
      for (int j = 0; j < 4; ++j) qv[j] = qbp[mrow[j]];
      size_t obase = ((size_t)(b * ENT + t)) * S_ * S_;
#pragma unroll
      for (int f = 0; f < 4; ++f) {
        float kv = kbp[ncol[f]];
#pragma unroll
        for (int j = 0; j < 4; ++j) {
          float v = (acc[f][j] + kv) + qv[j];
          v = v * mqv[j] - sqv[j];
          v = v * mkv[f] - skv[f];
          if (ncol[f] < mrow[j]) v -= NEGC;
          out[obase + (size_t)mrow[j] * S_ + ncol[f]] = v;
        }
      }
    }
  }
  // ---------------- arg head group ----------------
  {
    const short* qs = reinterpret_cast<const short*>(qwa);
    const short* ks = reinterpret_cast<const short*>(kwa);
    f32x4 acc[4] = {};
#pragma unroll
    for (int kk = 0; kk < 64; kk += 32) {
      s16x8 a = *reinterpret_cast<const s16x8*>(
          qs + (size_t)(b * S_ + m0 + (lane & 15)) * 64 + kk + kseg);
#pragma unroll
      for (int f = 0; f < 4; ++f) {
        s16x8 bb = *reinterpret_cast<const s16x8*>(
            ks + (size_t)(b * S_ + n0 + 16 * f + (lane & 15)) * 64 + kk + kseg);
        acc[f] = __builtin_amdgcn_mfma_f32_16x16x32_bf16(a, bb, acc[f], 0, 0, 0);
      }
    }
#pragma unroll
    for (int f = 0; f < 4; ++f)
#pragma unroll
      for (int j = 0; j < 4; ++j) acc[f][j] *= 0.125f;

    for (int t = 0; t < ARG; ++t) {
      const float* qbp = qba + ((size_t)b * ARG + t) * S_;
      const float* kbp = kba + ((size_t)b * ARG + t) * S_;
      float qv[4];
#pragma unroll
      for (int j = 0; j < 4; ++j) qv[j] = qbp[mrow[j]];
      size_t obase = OUT_ENT + ((size_t)(b * ARG + t)) * S_ * S_;
#pragma unroll
      for (int f = 0; f < 4; ++f) {
        float kv = kbp[ncol[f]];
#pragma unroll
        for (int j = 0; j < 4; ++j) {
          float v = (acc[f][j] + kv) + qv[j];
          v = v * mqv[j] - sqv[j];
          v = v * mkv[f] - skv[f];
          if (ncol[f] < mrow[j]) v -= NEGC;
          out[obase + (size_t)mrow[j] * S_ + ncol[f]] = v;
        }
      }
    }
  }
}

// ---------------------------------------------------------------------------
extern "C" void kernel_launch(void* const* d_in, const int* in_sizes, int n_in,
                              void* d_out, int out_size, void* d_ws, size_t ws_size,
                              hipStream_t stream) {
  (void)in_sizes; (void)n_in; (void)out_size; (void)ws_size;
  const float* X   = (const float*)d_in[0];
  const int* mask  = (const int*)d_in[1];
  const float* W1  = (const float*)d_in[2];
  const float* b1  = (const float*)d_in[3];
  const float* W2  = (const float*)d_in[4];
  const float* b2  = (const float*)d_in[5];
  const float* Wa1 = (const float*)d_in[6];
  const float* ba1 = (const float*)d_in[7];
  const float* Wa2 = (const float*)d_in[8];
  const float* ba2 = (const float*)d_in[9];
  float* out = (float*)d_out;

  char* ws = (char*)d_ws;
  size_t off = 0;
  auto walloc = [&](size_t bytes) -> void* {
    void* p = ws + off;
    off += (bytes + 255) & ~(size_t)255;
    return p;
  };
  __hip_bfloat16* Xb  = (__hip_bfloat16*)walloc((size_t)ROWS * H_ * 2);
  __hip_bfloat16* Wt  = (__hip_bfloat16*)walloc((size_t)NC * H_ * 2);
  float* bcat         = (float*)walloc((size_t)NC * 4);
  float* P            = (float*)walloc((size_t)ROWS * NC * 4);
  __hip_bfloat16* qwe = (__hip_bfloat16*)walloc((size_t)ROWS * 64 * 2);
  __hip_bfloat16* kwe = (__hip_bfloat16*)walloc((size_t)ROWS * 64 * 2);
  __hip_bfloat16* qwa = (__hip_bfloat16*)walloc((size_t)ROWS * 64 * 2);
  __hip_bfloat16* kwa = (__hip_bfloat16*)walloc((size_t)ROWS * 64 * 2);
  float* kbe = (float*)walloc((size_t)B_ * ENT * S_ * 4);
  float* qbe = (float*)walloc((size_t)B_ * ENT * S_ * 4);
  float* kba = (float*)walloc((size_t)B_ * ARG * S_ * 4);
  float* qba = (float*)walloc((size_t)B_ * ARG * S_ * 4);

  const int prep_tasks = ROWS * H_ / 4 + NC * H_ + NC;
  k_prep<<<dim3((prep_tasks + 255) / 256), dim3(256), 0, stream>>>(
      X, W1, b1, W2, b2, Wa1, ba1, Wa2, ba2, Xb, Wt, bcat);
  k_gemm<<<dim3(NC / 64, ROWS / 64), dim3(256), 0, stream>>>(Xb, Wt, bcat, P);
  k_rope<<<dim3(ROWS * 64 / 256), dim3(256), 0, stream>>>(
      P, qwe, kwe, qwa, kwa, kbe, qbe, kba, qba);
  k_bcast<<<dim3(8, 8, 8), dim3(256), 0, stream>>>(
      qwe, kwe, qwa, kwa, kbe, qbe, kba, qba, mask, out);
}